// Round 4
// baseline (1891.921 us; speedup 1.0000x reference)
//
#include <hip/hip_runtime.h>
#include <hip/hip_bf16.h>

#define LL 24
#define NN 16384
#define HH 128
#define KP 288           // padded K: 16 op + 56 attr + 32 fd + 32 od + 24 zero + 128 gh
#define KPAD 296         // LDS row stride (bf16): 592B = 16B-aligned, 2-way banks max
#define LN (LL*NN)

typedef __bf16 bf16;
typedef __attribute__((ext_vector_type(8))) __bf16 bf16x8;
typedef __attribute__((ext_vector_type(2))) __bf16 bf16x2;
typedef __attribute__((ext_vector_type(4))) float f32x4;

__device__ __forceinline__ float sigm(float x){ return 1.f/(1.f+__expf(-x)); }
__device__ __forceinline__ float tanhfast(float x){
    float e = __expf(-2.f*fabsf(x));
    float t = (1.f-e)/(1.f+e);
    return x >= 0.f ? t : -t;
}

// ---------------------------------------------------------------------------
// Transpose act weights: Wkf[k][ch] = Wf[ch][k] (74x32), Wko[k][ch] = Wo[ch][k]
// ---------------------------------------------------------------------------
__global__ void prep_wk(const float* __restrict__ Wf, const float* __restrict__ Wo,
                        float* __restrict__ Wkf, float* __restrict__ Wko)
{
    int t = blockIdx.x*64 + threadIdx.x;
    if (t < 74*32) {
        int k = t >> 5, ch = t & 31;
        Wkf[t] = Wf[ch*74 + k];
    } else if (t < 74*32 + 32*32) {
        int t2 = t - 74*32;
        int k = t2 >> 5, ch = t2 & 31;
        Wko[t2] = Wo[ch*32 + k];
    }
}

// ---------------------------------------------------------------------------
// act = leaky(X @ W.T + b) -> bf16, plus f32 per-channel sum/sumsq for BN.
// Thread owns ONE row x all 32 channels. x: bf16 in LDS (b32 per 2k, <=2-way
// banks). W: [k][ch] wave-uniform -> scalar loads, free FMA operand.
// ---------------------------------------------------------------------------
template<int D, int XP>
__global__ __launch_bounds__(256) void act_v3(
    const float* __restrict__ X, const float* __restrict__ Wk,
    const float* __restrict__ bias, bf16* __restrict__ act,
    float* __restrict__ sums)
{
    __shared__ bf16 xs[256*XP];
    const int tid  = threadIdx.x;
    const int lane = tid & 63;
    float s[32], q[32];
    #pragma unroll
    for (int ch=0; ch<32; ++ch){ s[ch]=0.f; q[ch]=0.f; }

    for (int g = blockIdx.x; g < LN/256; g += gridDim.x){
        const long row0 = (long)g*256;
        __syncthreads();
        for (int i = tid; i < 256*(D/2); i += 256){
            const int r = i/(D/2), j2 = i - r*(D/2);
            float2 v = *(const float2*)&X[(row0+r)*D + 2*j2];
            bf16x2 pk; pk[0]=(bf16)v.x; pk[1]=(bf16)v.y;
            *(bf16x2*)&xs[r*XP + 2*j2] = pk;
        }
        __syncthreads();

        float acc[32];
        #pragma unroll
        for (int ch=0; ch<32; ++ch) acc[ch] = bias[ch];
        #pragma unroll 2
        for (int k2=0; k2<D/2; ++k2){
            bf16x2 xv = *(const bf16x2*)&xs[tid*XP + 2*k2];
            const float x0 = (float)xv[0], x1 = (float)xv[1];
            const float* w0 = Wk + (2*k2)*32;
            const float* w1 = w0 + 32;
            #pragma unroll
            for (int ch=0; ch<32; ++ch){
                acc[ch] = fmaf(x0, w0[ch], acc[ch]);
                acc[ch] = fmaf(x1, w1[ch], acc[ch]);
            }
        }
        #pragma unroll
        for (int gch=0; gch<4; ++gch){
            bf16x8 pk;
            #pragma unroll
            for (int j=0; j<8; ++j){
                const int ch = gch*8+j;
                float v = acc[ch]; v = v>0.f ? v : 0.01f*v;
                pk[j] = (bf16)v;
                s[ch] += v; q[ch] += v*v;
            }
            *(bf16x8*)&act[(row0+tid)*32 + gch*8] = pk;
        }
    }

    // wave butterfly reduce all 64 stats, then 2 atomics per owning lane
    #pragma unroll
    for (int ch=0; ch<32; ++ch){
        float v = s[ch], u = q[ch];
        #pragma unroll
        for (int off=32; off>0; off>>=1){
            v += __shfl_xor(v, off, 64);
            u += __shfl_xor(u, off, 64);
        }
        s[ch]=v; q[ch]=u;
    }
    if (lane < 32){
        atomicAdd(&sums[lane],    s[lane]);
        atomicAdd(&sums[32+lane], q[lane]);
    }
}

// ---------------------------------------------------------------------------
// Wtb[n'][k] bf16, gate-interleaved column permutation:
// n' = group*64 + gate*16 + c16  ->  orig j = gate*128 + group*16 + c16
// ---------------------------------------------------------------------------
__global__ void prep_wtb(const float* __restrict__ Wih, const float* __restrict__ Whh,
                         const float* __restrict__ bih, const float* __restrict__ bhh,
                         bf16* __restrict__ Wtb, float* __restrict__ b4p)
{
    const int np = blockIdx.x;
    const int k  = threadIdx.x;
    const int gate = (np>>4)&3;
    const int j = gate*128 + (np>>6)*16 + (np&15);
    if (k < KP) {
        float v = 0.f;
        if (k < 136)      v = Wih[(long)j*136 + k];
        else if (k >= 160) v = Whh[(long)j*128 + (k-160)];
        Wtb[(long)np*KP + k] = (bf16)v;
    }
    if (k == 0) b4p[np] = bih[j] + bhh[j];
}

// ---------------------------------------------------------------------------
// BN scale/shift + collapse W2@W1 head.
// ---------------------------------------------------------------------------
__global__ void prep_stats(const float* __restrict__ stats,
    const float* __restrict__ g1, const float* __restrict__ beta1,
    const float* __restrict__ g2, const float* __restrict__ beta2,
    const float* __restrict__ W1, const float* __restrict__ b1,
    const float* __restrict__ W2, const float* __restrict__ b2,
    float* __restrict__ ss, float* __restrict__ wvb)
{
    const int t = threadIdx.x;
    const float inv = 1.f/(float)LN;
    if (t < 32) {
        float mean = stats[t]*inv;
        float var  = stats[32+t]*inv - mean*mean;
        float sc = g1[t]/sqrtf(var + 1e-5f);
        ss[t] = sc; ss[32+t] = beta1[t] - mean*sc;
    } else if (t < 64) {
        int c = t - 32;
        float mean = stats[64+c]*inv;
        float var  = stats[96+c]*inv - mean*mean;
        float sc = g2[c]/sqrtf(var + 1e-5f);
        ss[64+c] = sc; ss[96+c] = beta2[c] - mean*sc;
    }
    float s = 0.f;
    for (int a=0;a<20;++a) s += W2[a]*W1[a*HH + t];
    wvb[t] = s;
    if (t == 0) {
        float sb = 0.f;
        for (int a=0;a<20;++a) sb += W2[a]*b1[a];
        wvb[128] = sb + b2[0];
    }
}

// ---------------------------------------------------------------------------
// Fused LSTM step: build A-tile in LDS + barrier-free MFMA K-loop + LSTM cell.
// Grid (128,4): bm = m-tile (fast dim -> bn-siblings share XCD), bn = n-tile.
// B fragments held in VGPRs (loaded once); A staged in LDS by the block.
// ---------------------------------------------------------------------------
__global__ __launch_bounds__(256, 2) void lstm_fused(
    const float* __restrict__ op, const float* __restrict__ attr,
    const bf16* __restrict__ actf, const bf16* __restrict__ acto,
    const int* __restrict__ map, const float* __restrict__ ss,
    const bf16* __restrict__ Wtb, const float* __restrict__ b4p,
    const bf16* __restrict__ h_prev, const float* __restrict__ c_prev,
    bf16* __restrict__ h_next, float* __restrict__ c_next,
    int l, int first)
{
    __shared__ bf16 As[128*KPAD];          // 75,776 B -> 2 blocks/CU
    const int tid  = threadIdx.x;
    const int bm   = blockIdx.x;
    const int bn   = blockIdx.y;
    const int m0   = bm*128, n0p = bn*128;
    const int lane = tid & 63, w = tid >> 6;
    const int wr   = w >> 1,  wc = w & 1;
    const long lbase = (long)l * NN;

    // ---- build A tile in LDS: rows m0..m0+127, layout [op|attr|fd|od|0|gh]
    for (int i = tid; i < 128*36; i += 256) {
        const int r = i / 36, c = i - r*36;
        const long e = lbase + m0 + r;
        const int k0 = c*8;
        bf16x8 out;
        if (c < 9) {                                   // op (c<2) or attr
            const float* src = (c < 2) ? (op + e*16 + k0) : (attr + e*56 + (k0-16));
            float4 f0 = *(const float4*)src;
            float4 f1 = *(const float4*)(src+4);
            out[0]=(bf16)f0.x; out[1]=(bf16)f0.y; out[2]=(bf16)f0.z; out[3]=(bf16)f0.w;
            out[4]=(bf16)f1.x; out[5]=(bf16)f1.y; out[6]=(bf16)f1.z; out[7]=(bf16)f1.w;
        } else if (c < 17) {                           // fd / od with BN fold
            const int ch = (c < 13) ? (k0-72) : (k0-104);
            const bf16* src = (c < 13) ? (actf + e*32 + ch) : (acto + e*32 + ch);
            const float* sp = ss + ((c < 13) ? 0 : 64);
            bf16x8 v = *(const bf16x8*)src;
            #pragma unroll
            for (int j=0;j<8;++j)
                out[j] = (bf16)fmaf((float)v[j], sp[ch+j], sp[32+ch+j]);
        } else if (c < 20) {                           // zero pad
            #pragma unroll
            for (int j=0;j<8;++j) out[j] = (bf16)0.f;
        } else {                                       // gh gather
            const int jj = k0 - 160;
            float g[8] = {0,0,0,0,0,0,0,0};
            if (!first) {
                int2 mp = *(const int2*)&map[e*2];
                if (mp.x) { bf16x8 v = *(const bf16x8*)&h_prev[(long)(mp.x-1)*HH + jj];
                    #pragma unroll
                    for (int j=0;j<8;++j) g[j] += (float)v[j]; }
                if (mp.y) { bf16x8 v = *(const bf16x8*)&h_prev[(long)(mp.y-1)*HH + jj];
                    #pragma unroll
                    for (int j=0;j<8;++j) g[j] += (float)v[j]; }
            }
            #pragma unroll
            for (int j=0;j<8;++j) out[j] = (bf16)(0.5f*g[j]);
        }
        *(bf16x8*)&As[r*KPAD + k0] = out;
    }

    // ---- load all B fragments into VGPRs (36 x bf16x8 = 144 VGPR)
    bf16x8 bq[9][4];
    {
        const bf16* Bb = Wtb + (size_t)n0p*KP;
        const int nb  = wc*64 + (lane&15);
        const int kof = (lane>>4)*8;
        #pragma unroll
        for (int kk=0; kk<9; ++kk)
            #pragma unroll
            for (int t4=0; t4<4; ++t4)
                bq[kk][t4] = *(const bf16x8*)&Bb[(size_t)(nb + t4*16)*KP + kk*32 + kof];
    }

    f32x4 acc[4][4];
    #pragma unroll
    for (int ni=0; ni<4; ++ni){
        float b = b4p[n0p + wc*64 + ni*16 + (lane&15)];
        #pragma unroll
        for (int mi=0; mi<4; ++mi) acc[mi][ni] = (f32x4){b,b,b,b};
    }

    __syncthreads();

    // ---- barrier-free K-loop: 4 LDS reads + 16 MFMA per kk
    #pragma unroll
    for (int kk=0; kk<9; ++kk){
        bf16x8 af[4];
        #pragma unroll
        for (int mi=0; mi<4; ++mi)
            af[mi] = *(const bf16x8*)&As[(wr*64 + mi*16 + (lane&15))*KPAD
                                         + kk*32 + (lane>>4)*8];
        #pragma unroll
        for (int mi=0; mi<4; ++mi)
            #pragma unroll
            for (int ni=0; ni<4; ++ni)
                acc[mi][ni] = __builtin_amdgcn_mfma_f32_16x16x32_bf16(
                    af[mi], bq[kk][ni], acc[mi][ni], 0, 0, 0);
    }

    // ---- fused LSTM cell epilogue: acc[mi][0..3] = gates i,f,g,o, same lane
    const int cell = bn*32 + wc*16 + (lane&15);
    #pragma unroll
    for (int mi=0; mi<4; ++mi){
        const int rbase = m0 + wr*64 + mi*16 + (lane>>4)*4;
        #pragma unroll
        for (int reg=0; reg<4; ++reg){
            const int n = rbase + reg;
            float gc = 0.f;
            if (!first){
                int2 mp = *(const int2*)&map[(lbase+n)*2];
                if (mp.x) gc += c_prev[(long)(mp.x-1)*HH + cell];
                if (mp.y) gc += c_prev[(long)(mp.y-1)*HH + cell];
                gc *= 0.5f;
            }
            float cn = sigm(acc[mi][1][reg])*gc
                     + sigm(acc[mi][0][reg])*tanhfast(acc[mi][2][reg]);
            float hn = sigm(acc[mi][3][reg])*tanhfast(cn);
            c_next[(long)n*HH + cell] = cn;
            h_next[(long)n*HH + cell] = (bf16)hn;
        }
    }
}

// ---------------------------------------------------------------------------
// out[n] = sigmoid(h[n] . wv + wb); one wave per row.
// ---------------------------------------------------------------------------
__global__ __launch_bounds__(256) void final_k(
    const bf16* __restrict__ h, const float* __restrict__ wvb,
    float* __restrict__ out, int rows)
{
    int gt = blockIdx.x*256 + threadIdx.x;
    int row = gt >> 6;
    int lane = gt & 63;
    if (row >= rows) return;
    float v = fmaf((float)h[(long)row*HH + lane], wvb[lane],
                   (float)h[(long)row*HH + 64 + lane] * wvb[64+lane]);
    #pragma unroll
    for (int off=32; off>0; off>>=1) v += __shfl_down(v, off);
    if (lane == 0) out[row] = sigm(v + wvb[128]);
}

extern "C" void kernel_launch(void* const* d_in, const int* in_sizes, int n_in,
                              void* d_out, int out_size, void* d_ws, size_t ws_size,
                              hipStream_t stream)
{
    const float* op      = (const float*)d_in[0];
    const float* attr    = (const float*)d_in[1];
    const float* filt    = (const float*)d_in[2];
    const float* outp    = (const float*)d_in[3];
    const int*   mapping = (const int*)d_in[4];
    const float* Wf  = (const float*)d_in[6];
    const float* bf_ = (const float*)d_in[7];
    const float* Wo  = (const float*)d_in[8];
    const float* bo  = (const float*)d_in[9];
    const float* g1  = (const float*)d_in[10];
    const float* be1 = (const float*)d_in[11];
    const float* g2  = (const float*)d_in[12];
    const float* be2 = (const float*)d_in[13];
    const float* Wih = (const float*)d_in[14];
    const float* Whh = (const float*)d_in[15];
    const float* bih = (const float*)d_in[16];
    const float* bhh = (const float*)d_in[17];
    const float* W1  = (const float*)d_in[18];
    const float* b1  = (const float*)d_in[19];
    const float* W2  = (const float*)d_in[20];
    const float* b2  = (const float*)d_in[21];

    char* p = (char*)d_ws;
    auto alloc = [&](size_t bytes){ char* r = p; p += (bytes + 255) & ~255ull; return r; };
    bf16* actf = (bf16*)alloc((size_t)LN*32*2);
    bf16* acto = (bf16*)alloc((size_t)LN*32*2);
    bf16* h0   = (bf16*)alloc((size_t)NN*HH*2);
    bf16* h1   = (bf16*)alloc((size_t)NN*HH*2);
    float* c0  = (float*)alloc((size_t)NN*HH*4);
    float* c1  = (float*)alloc((size_t)NN*HH*4);
    bf16* Wtb  = (bf16*)alloc((size_t)512*KP*2);
    float* Wkf = (float*)alloc(74*32*4);
    float* Wko = (float*)alloc(32*32*4);
    float* b4p = (float*)alloc(512*4);
    float* stats=(float*)alloc(128*4);
    float* ssb = (float*)alloc(128*4);
    float* wvb = (float*)alloc(132*4);

    prep_wk<<<53, 64, 0, stream>>>(Wf, Wo, Wkf, Wko);
    prep_wtb<<<512, 320, 0, stream>>>(Wih, Whh, bih, bhh, Wtb, b4p);
    hipMemsetAsync(stats, 0, 128*sizeof(float), stream);
    act_v3<74,76><<<768, 256, 0, stream>>>(filt, Wkf, bf_, actf, stats);
    act_v3<32,34><<<768, 256, 0, stream>>>(outp, Wko, bo, acto, stats+64);
    prep_stats<<<1, 128, 0, stream>>>(stats, g1, be1, g2, be2, W1, b1, W2, b2, ssb, wvb);

    bf16*  hb[2] = {h0, h1};
    float* cb[2] = {c0, c1};
    for (int t = 0; t < LL; ++t) {
        const int l = (LL-1) - t;
        lstm_fused<<<dim3(128,4), 256, 0, stream>>>(op, attr, actf, acto, mapping, ssb,
            Wtb, b4p, hb[t&1], cb[t&1], hb[(t+1)&1], cb[(t+1)&1], l, t==0);
    }
    final_k<<<(out_size*64 + 255)/256, 256, 0, stream>>>(hb[0], wvb, (float*)d_out, out_size);
}